// Round 1
// baseline (3502.290 us; speedup 1.0000x reference)
//
#include <hip/hip_runtime.h>

#define N_NODES 100000
#define N_EDGES 1600000
#define DIM 128  // DIM_IN == DIM_OUT == 128

// ---------------------------------------------------------------------------
// Kernel 1: zero d_out (harness poisons it with 0xAA before every launch)
// ---------------------------------------------------------------------------
__global__ __launch_bounds__(256) void zero_out_kernel(float4* __restrict__ out) {
    int i = blockIdx.x * 256 + threadIdx.x;
    if (i < N_NODES * DIM / 4)
        out[i] = make_float4(0.f, 0.f, 0.f, 0.f);
}

// ---------------------------------------------------------------------------
// Kernel 2: h = x @ W^T   (h[n][o] = sum_k x[n][k] * W[o][k])
// Block = 128 threads; thread o owns output column o and keeps W[o][:] in
// 32 float4 registers. x-row loads are wave-uniform (one broadcast
// transaction, L1-cached); h stores are fully coalesced (lane o -> col o).
// 4 independent partial sums hide the v_fma_f32 dep latency (~4 cyc).
// ---------------------------------------------------------------------------
#define GEMM_ROWS_PER_BLOCK 32
__global__ __launch_bounds__(128) void gemm_xwt_kernel(
        const float4* __restrict__ x4,   // [N_NODES][32]
        const float4* __restrict__ W4,   // [DIM][32]
        float* __restrict__ h)           // [N_NODES][DIM]
{
    const int o = threadIdx.x;  // 0..127 output column

    float4 w[32];
#pragma unroll
    for (int k = 0; k < 32; ++k) w[k] = W4[o * 32 + k];

    const int row0 = blockIdx.x * GEMM_ROWS_PER_BLOCK;
    const int row1 = min(row0 + GEMM_ROWS_PER_BLOCK, N_NODES);

    for (int r = row0; r < row1; ++r) {
        const float4* xr = x4 + (size_t)r * 32;
        float a0 = 0.f, a1 = 0.f, a2 = 0.f, a3 = 0.f;
#pragma unroll
        for (int k = 0; k < 32; ++k) {
            float4 xv = xr[k];  // wave-uniform address -> broadcast
            a0 += xv.x * w[k].x;
            a1 += xv.y * w[k].y;
            a2 += xv.z * w[k].z;
            a3 += xv.w * w[k].w;
        }
        h[(size_t)r * DIM + o] = (a0 + a1) + (a2 + a3);
    }
}

// ---------------------------------------------------------------------------
// Kernel 3: out[dst[e]] += vals[e] * h[src[e]]
// 32 lanes per edge; lane handles 4 contiguous floats (float4 gather,
// 4x fp32 atomicAdd scatter). src/dst/vals loads are uniform per edge-group.
// ---------------------------------------------------------------------------
__global__ __launch_bounds__(256) void scatter_kernel(
        const float* __restrict__ h,
        const float* __restrict__ vals,
        const int* __restrict__ src,
        const int* __restrict__ dst,
        float* __restrict__ out)
{
    const int lane = threadIdx.x & 31;
    int e = (blockIdx.x * 256 + threadIdx.x) >> 5;
    const int estride = (gridDim.x * 256) >> 5;

    for (; e < N_EDGES; e += estride) {
        const int   s = src[e];
        const int   d = dst[e];
        const float v = vals[e];

        float4 hv = ((const float4*)(h + (size_t)s * DIM))[lane];
        float* op = out + (size_t)d * DIM + lane * 4;
        atomicAdd(op + 0, v * hv.x);
        atomicAdd(op + 1, v * hv.y);
        atomicAdd(op + 2, v * hv.z);
        atomicAdd(op + 3, v * hv.w);
    }
}

// ---------------------------------------------------------------------------
extern "C" void kernel_launch(void* const* d_in, const int* in_sizes, int n_in,
                              void* d_out, int out_size, void* d_ws, size_t ws_size,
                              hipStream_t stream) {
    const float* x    = (const float*)d_in[0];  // [N_NODES, DIM]
    const float* W    = (const float*)d_in[1];  // [DIM, DIM]
    const float* vals = (const float*)d_in[2];  // [N_EDGES]
    const int*   src  = (const int*)d_in[3];    // [N_EDGES]
    const int*   dst  = (const int*)d_in[4];    // [N_EDGES]
    float* out = (float*)d_out;                 // [N_NODES, DIM]
    float* h   = (float*)d_ws;                  // [N_NODES, DIM] scratch (51.2 MB)

    // 1) zero the (poisoned) output
    {
        int n4 = N_NODES * DIM / 4;
        zero_out_kernel<<<(n4 + 255) / 256, 256, 0, stream>>>((float4*)out);
    }
    // 2) h = x @ W^T
    {
        int grid = (N_NODES + GEMM_ROWS_PER_BLOCK - 1) / GEMM_ROWS_PER_BLOCK;
        gemm_xwt_kernel<<<grid, 128, 0, stream>>>(
            (const float4*)x, (const float4*)W, h);
    }
    // 3) scatter-add messages
    {
        int edge_groups_per_block = 256 / 32;                   // 8
        int grid = (N_EDGES + edge_groups_per_block - 1) / edge_groups_per_block;
        scatter_kernel<<<grid, 256, 0, stream>>>(h, vals, src, dst, out);
    }
}

// Round 2
// 490.145 us; speedup vs baseline: 7.1454x; 7.1454x over previous
//
#include <hip/hip_runtime.h>

#define N_NODES 100000
#define N_EDGES 1600000
#define DIM 128

// ---------------- workspace layout (bytes, all 128-aligned) ----------------
#define OFF_H       0                         // float [N_NODES][128]  51,200,000
#define OFF_ROWPTR  51200000                  // int   [N_NODES+1]        400,128
#define OFF_CURSOR  51600128                  // int   [N_NODES]          400,128
#define OFF_COUNTS  52000256                  // int   [N_NODES]          400,128
#define OFF_SSRC    52400384                  // int   [N_EDGES]        6,400,000
#define OFF_SVAL    58800384                  // float [N_EDGES]        6,400,000
#define WS_NEED     65200384

// ---------------------------------------------------------------------------
// zero helpers
// ---------------------------------------------------------------------------
__global__ __launch_bounds__(256) void zero_out_kernel(float4* __restrict__ out) {
    int i = blockIdx.x * 256 + threadIdx.x;
    if (i < N_NODES * DIM / 4) out[i] = make_float4(0.f, 0.f, 0.f, 0.f);
}

__global__ __launch_bounds__(256) void zero_counts_kernel(int4* __restrict__ c4) {
    int i = blockIdx.x * 256 + threadIdx.x;
    if (i < 100032 / 4) c4[i] = make_int4(0, 0, 0, 0);
}

// ---------------------------------------------------------------------------
// GEMM h = x @ W^T, LDS-tiled. 64 rows x 128 cols per block, 256 threads,
// 4x8 micro-tile. xs[r][k] reads are 16-lane broadcasts (2-way alias = free);
// wsh stored k-major so the W fragment is 2x ds_read_b128.
// LDS = 51.2 KB -> 3 blocks/CU.
// ---------------------------------------------------------------------------
#define GR 64
__global__ __launch_bounds__(256) void gemm_tiled_kernel(
        const float4* __restrict__ x4,   // [N_NODES][32]
        const float4* __restrict__ W4,   // [128][32]
        float* __restrict__ h)           // [N_NODES][128]
{
    __shared__ float xs[GR][68];     // [row][k-chunk 64], pad 68 (16B-div rows)
    __shared__ float wsh[64][132];   // wsh[kk][c] = W[c][kc*64+kk], pad 132

    const int t  = threadIdx.x;
    const int tx = t & 15;           // col group: cols 8*tx..8*tx+7
    const int ty = t >> 4;           // row group: rows 4*ty..4*ty+3
    const int r0 = blockIdx.x * GR;

    float acc[4][8];
#pragma unroll
    for (int i = 0; i < 4; ++i)
#pragma unroll
        for (int j = 0; j < 8; ++j) acc[i][j] = 0.f;

    for (int kc = 0; kc < 2; ++kc) {
        // stage x-tile: 64 rows x 16 float4 (coalesced)
#pragma unroll
        for (int i = 0; i < 4; ++i) {
            int linear = t + 256 * i;        // 0..1023
            int r  = linear >> 4;
            int k4 = linear & 15;
            float4 v = make_float4(0.f, 0.f, 0.f, 0.f);
            if (r0 + r < N_NODES) v = x4[(size_t)(r0 + r) * 32 + kc * 16 + k4];
            *(float4*)&xs[r][k4 * 4] = v;
        }
        // stage W chunk transposed: 128 cols x 16 float4 (coalesced read)
#pragma unroll
        for (int i = 0; i < 8; ++i) {
            int linear = t + 256 * i;        // 0..2047
            int c  = linear >> 4;
            int k4 = linear & 15;
            float4 v = W4[(size_t)c * 32 + kc * 16 + k4];
            wsh[k4 * 4 + 0][c] = v.x;
            wsh[k4 * 4 + 1][c] = v.y;
            wsh[k4 * 4 + 2][c] = v.z;
            wsh[k4 * 4 + 3][c] = v.w;
        }
        __syncthreads();

#pragma unroll 4
        for (int kk = 0; kk < 64; ++kk) {
            float xf[4], wf[8];
#pragma unroll
            for (int i = 0; i < 4; ++i) xf[i] = xs[ty * 4 + i][kk];
            float4 wlo = *(const float4*)&wsh[kk][tx * 8];
            float4 whi = *(const float4*)&wsh[kk][tx * 8 + 4];
            wf[0] = wlo.x; wf[1] = wlo.y; wf[2] = wlo.z; wf[3] = wlo.w;
            wf[4] = whi.x; wf[5] = whi.y; wf[6] = whi.z; wf[7] = whi.w;
#pragma unroll
            for (int i = 0; i < 4; ++i)
#pragma unroll
                for (int j = 0; j < 8; ++j) acc[i][j] += xf[i] * wf[j];
        }
        __syncthreads();
    }

#pragma unroll
    for (int i = 0; i < 4; ++i) {
        int r = r0 + ty * 4 + i;
        if (r < N_NODES) {
            float4 lo = make_float4(acc[i][0], acc[i][1], acc[i][2], acc[i][3]);
            float4 hi = make_float4(acc[i][4], acc[i][5], acc[i][6], acc[i][7]);
            *(float4*)&h[(size_t)r * DIM + tx * 8]     = lo;
            *(float4*)&h[(size_t)r * DIM + tx * 8 + 4] = hi;
        }
    }
}

// ---------------------------------------------------------------------------
// CSR build: histogram -> scan -> bucket fill
// ---------------------------------------------------------------------------
__global__ __launch_bounds__(256) void hist_kernel(const int* __restrict__ dst,
                                                   int* __restrict__ counts) {
    int e = blockIdx.x * 256 + threadIdx.x;
    if (e < N_EDGES) atomicAdd(&counts[dst[e]], 1);
}

// single block, 1024 threads: exclusive scan of counts[0..N) -> row_ptr, cursor
__global__ __launch_bounds__(1024) void scan_kernel(const int* __restrict__ counts,
                                                    int* __restrict__ row_ptr,
                                                    int* __restrict__ cursor) {
    __shared__ int wsum[16];
    const int t    = threadIdx.x;
    const int lane = t & 63;
    const int wv   = t >> 6;
    int running = 0;

    for (int base = 0; base < N_NODES; base += 4096) {
        int idx = base + t * 4;
        int4 c = make_int4(0, 0, 0, 0);
        if (idx < N_NODES)  // N_NODES % 4 == 0 -> whole pack in-bounds
            c = *(const int4*)(counts + idx);
        int s = c.x + c.y + c.z + c.w;

        // inclusive wave scan of s
        int v = s;
#pragma unroll
        for (int off = 1; off < 64; off <<= 1) {
            int u = __shfl_up(v, off, 64);
            if (lane >= off) v += u;
        }
        if (lane == 63) wsum[wv] = v;
        __syncthreads();
        if (wv == 0 && lane < 16) {
            int ws = wsum[lane];
#pragma unroll
            for (int off = 1; off < 16; off <<= 1) {
                int u = __shfl_up(ws, off, 64);
                if (lane >= off) ws += u;
            }
            wsum[lane] = ws;  // inclusive scan of wave sums
        }
        __syncthreads();

        int wave_excl   = (wv == 0) ? 0 : wsum[wv - 1];
        int chunk_total = wsum[15];
        int p = running + wave_excl + (v - s);  // exclusive prefix for this pack

        if (idx < N_NODES) {
            int4 r;
            r.x = p;
            r.y = p + c.x;
            r.z = r.y + c.y;
            r.w = r.z + c.z;
            *(int4*)(row_ptr + idx) = r;
            *(int4*)(cursor  + idx) = r;
        }
        running += chunk_total;
        __syncthreads();  // protect wsum before next chunk
    }
    if (t == 0) row_ptr[N_NODES] = running;
}

__global__ __launch_bounds__(256) void fill_kernel(const int* __restrict__ src,
                                                   const int* __restrict__ dst,
                                                   const float* __restrict__ vals,
                                                   int* __restrict__ cursor,
                                                   int* __restrict__ ssrc,
                                                   float* __restrict__ sval) {
    int e = blockIdx.x * 256 + threadIdx.x;
    if (e < N_EDGES) {
        int pos = atomicAdd(&cursor[dst[e]], 1);
        ssrc[pos] = src[e];
        sval[pos] = vals[e];
    }
}

// ---------------------------------------------------------------------------
// Gather: one wave per node. out[i] = sum_{j in row i} val[j] * h[ssrc[j]]
// Lane holds float2 (64 lanes x 8 B = one 512 B row). Unroll-2 for MLP.
// No atomics; every out row written exactly once (handles 0xAA poison).
// ---------------------------------------------------------------------------
__global__ __launch_bounds__(256) void gather_kernel(
        const float2* __restrict__ h2,
        const int* __restrict__ row_ptr,
        const int* __restrict__ ssrc,
        const float* __restrict__ sval,
        float2* __restrict__ out2)
{
    const int lane = threadIdx.x & 63;
    const int node = blockIdx.x * 4 + (threadIdx.x >> 6);
    if (node >= N_NODES) return;

    const int jb = row_ptr[node];
    const int je = row_ptr[node + 1];

    float2 acc0 = make_float2(0.f, 0.f);
    float2 acc1 = make_float2(0.f, 0.f);

    int j = jb;
    for (; j + 1 < je; j += 2) {
        int   s0 = ssrc[j],  s1 = ssrc[j + 1];
        float v0 = sval[j],  v1 = sval[j + 1];
        float2 a = h2[(size_t)s0 * 64 + lane];
        float2 b = h2[(size_t)s1 * 64 + lane];
        acc0.x += v0 * a.x; acc0.y += v0 * a.y;
        acc1.x += v1 * b.x; acc1.y += v1 * b.y;
    }
    if (j < je) {
        int s = ssrc[j];
        float v = sval[j];
        float2 a = h2[(size_t)s * 64 + lane];
        acc0.x += v * a.x; acc0.y += v * a.y;
    }
    acc0.x += acc1.x; acc0.y += acc1.y;
    out2[(size_t)node * 64 + lane] = acc0;
}

// ---------------------------------------------------------------------------
// Fallback scatter (atomic) if workspace is too small for CSR arrays
// ---------------------------------------------------------------------------
__global__ __launch_bounds__(256) void scatter_kernel(
        const float* __restrict__ h, const float* __restrict__ vals,
        const int* __restrict__ src, const int* __restrict__ dst,
        float* __restrict__ out)
{
    const int lane = threadIdx.x & 31;
    int e = (blockIdx.x * 256 + threadIdx.x) >> 5;
    if (e >= N_EDGES) return;
    const int   s = src[e];
    const int   d = dst[e];
    const float v = vals[e];
    float4 hv = ((const float4*)(h + (size_t)s * DIM))[lane];
    float* op = out + (size_t)d * DIM + lane * 4;
    atomicAdd(op + 0, v * hv.x);
    atomicAdd(op + 1, v * hv.y);
    atomicAdd(op + 2, v * hv.z);
    atomicAdd(op + 3, v * hv.w);
}

// ---------------------------------------------------------------------------
extern "C" void kernel_launch(void* const* d_in, const int* in_sizes, int n_in,
                              void* d_out, int out_size, void* d_ws, size_t ws_size,
                              hipStream_t stream) {
    const float* x    = (const float*)d_in[0];
    const float* W    = (const float*)d_in[1];
    const float* vals = (const float*)d_in[2];
    const int*   src  = (const int*)d_in[3];
    const int*   dst  = (const int*)d_in[4];
    float* out = (float*)d_out;

    char* ws = (char*)d_ws;
    float* h       = (float*)(ws + OFF_H);
    int*   row_ptr = (int*)  (ws + OFF_ROWPTR);
    int*   cursor  = (int*)  (ws + OFF_CURSOR);
    int*   counts  = (int*)  (ws + OFF_COUNTS);
    int*   ssrc    = (int*)  (ws + OFF_SSRC);
    float* sval    = (float*)(ws + OFF_SVAL);

    // GEMM: h = x @ W^T
    {
        int grid = (N_NODES + GR - 1) / GR;  // 1563
        gemm_tiled_kernel<<<grid, 256, 0, stream>>>(
            (const float4*)x, (const float4*)W, h);
    }

    if (ws_size >= (size_t)WS_NEED) {
        // CSR build
        zero_counts_kernel<<<(100032 / 4 + 255) / 256, 256, 0, stream>>>((int4*)counts);
        hist_kernel<<<(N_EDGES + 255) / 256, 256, 0, stream>>>(dst, counts);
        scan_kernel<<<1, 1024, 0, stream>>>(counts, row_ptr, cursor);
        fill_kernel<<<(N_EDGES + 255) / 256, 256, 0, stream>>>(src, dst, vals,
                                                               cursor, ssrc, sval);
        // gather (writes every out row exactly once)
        gather_kernel<<<(N_NODES + 3) / 4, 256, 0, stream>>>(
            (const float2*)h, row_ptr, ssrc, sval, (float2*)out);
    } else {
        // fallback: atomic scatter
        zero_out_kernel<<<(N_NODES * DIM / 4 + 255) / 256, 256, 0, stream>>>((float4*)out);
        int grid = (N_EDGES * 32 + 255) / 256;
        scatter_kernel<<<grid, 256, 0, stream>>>(h, vals, src, dst, out);
    }
}

// Round 3
// 444.339 us; speedup vs baseline: 7.8820x; 1.1031x over previous
//
#include <hip/hip_runtime.h>

#define N_NODES 100000
#define N_EDGES 1600000
#define DIM 128
#define NBLK_SCAN 98   // ceil(100000 / 1024)

// ---------------- workspace layout (bytes, 128-aligned) --------------------
#define OFF_H       0                    // bf16 [N_NODES][128]   25,600,000
#define OFF_ROWPTR  25600000             // int  [N_NODES+1]         400,128
#define OFF_CURSOR  26000128             // int  [N_NODES]           400,128
#define OFF_COUNTS  26400256             // int  [N_NODES pad]       400,128
#define OFF_BSUM    26800384             // int  [98] + int [98]       1,024
#define OFF_EPACK   26801408             // uint2 [N_EDGES]       12,800,000
#define WS_NEED     39601408

static __device__ __forceinline__ unsigned short f2bf(float f) {
    union { float f; unsigned u; } a; a.f = f;
    unsigned r = a.u + 0x7fffu + ((a.u >> 16) & 1u);  // round-to-nearest-even
    return (unsigned short)(r >> 16);
}

// ---------------------------------------------------------------------------
// zero helpers
// ---------------------------------------------------------------------------
__global__ __launch_bounds__(256) void zero_out_kernel(float4* __restrict__ out) {
    int i = blockIdx.x * 256 + threadIdx.x;
    if (i < N_NODES * DIM / 4) out[i] = make_float4(0.f, 0.f, 0.f, 0.f);
}

__global__ __launch_bounds__(256) void zero_counts_kernel(int4* __restrict__ c4) {
    int i = blockIdx.x * 256 + threadIdx.x;
    if (i < 100032 / 4) c4[i] = make_int4(0, 0, 0, 0);
}

// ---------------------------------------------------------------------------
// GEMM h = x @ W^T (fp32 accumulate, bf16 output).
// 64 rows x 128 cols per block, 256 threads, 4x8 micro-tile.
// ---------------------------------------------------------------------------
#define GR 64
__global__ __launch_bounds__(256) void gemm_tiled_kernel(
        const float4* __restrict__ x4,        // [N_NODES][32]
        const float4* __restrict__ W4,        // [128][32]
        unsigned int* __restrict__ hbits)     // [N_NODES][64] (2 bf16 / uint)
{
    __shared__ float xs[GR][68];
    __shared__ float wsh[64][132];

    const int t  = threadIdx.x;
    const int tx = t & 15;           // cols 8*tx..8*tx+7
    const int ty = t >> 4;           // rows 4*ty..4*ty+3
    const int r0 = blockIdx.x * GR;

    float acc[4][8];
#pragma unroll
    for (int i = 0; i < 4; ++i)
#pragma unroll
        for (int j = 0; j < 8; ++j) acc[i][j] = 0.f;

    for (int kc = 0; kc < 2; ++kc) {
#pragma unroll
        for (int i = 0; i < 4; ++i) {
            int linear = t + 256 * i;
            int r  = linear >> 4;
            int k4 = linear & 15;
            float4 v = make_float4(0.f, 0.f, 0.f, 0.f);
            if (r0 + r < N_NODES) v = x4[(size_t)(r0 + r) * 32 + kc * 16 + k4];
            *(float4*)&xs[r][k4 * 4] = v;
        }
#pragma unroll
        for (int i = 0; i < 8; ++i) {
            int linear = t + 256 * i;
            int c  = linear >> 4;
            int k4 = linear & 15;
            float4 v = W4[(size_t)c * 32 + kc * 16 + k4];
            wsh[k4 * 4 + 0][c] = v.x;
            wsh[k4 * 4 + 1][c] = v.y;
            wsh[k4 * 4 + 2][c] = v.z;
            wsh[k4 * 4 + 3][c] = v.w;
        }
        __syncthreads();

#pragma unroll 4
        for (int kk = 0; kk < 64; ++kk) {
            float xf[4], wf[8];
#pragma unroll
            for (int i = 0; i < 4; ++i) xf[i] = xs[ty * 4 + i][kk];
            float4 wlo = *(const float4*)&wsh[kk][tx * 8];
            float4 whi = *(const float4*)&wsh[kk][tx * 8 + 4];
            wf[0] = wlo.x; wf[1] = wlo.y; wf[2] = wlo.z; wf[3] = wlo.w;
            wf[4] = whi.x; wf[5] = whi.y; wf[6] = whi.z; wf[7] = whi.w;
#pragma unroll
            for (int i = 0; i < 4; ++i)
#pragma unroll
                for (int j = 0; j < 8; ++j) acc[i][j] += xf[i] * wf[j];
        }
        __syncthreads();
    }

#pragma unroll
    for (int i = 0; i < 4; ++i) {
        int r = r0 + ty * 4 + i;
        if (r < N_NODES) {
            uint4 u;
            u.x = (unsigned)f2bf(acc[i][0]) | ((unsigned)f2bf(acc[i][1]) << 16);
            u.y = (unsigned)f2bf(acc[i][2]) | ((unsigned)f2bf(acc[i][3]) << 16);
            u.z = (unsigned)f2bf(acc[i][4]) | ((unsigned)f2bf(acc[i][5]) << 16);
            u.w = (unsigned)f2bf(acc[i][6]) | ((unsigned)f2bf(acc[i][7]) << 16);
            *(uint4*)&hbits[(size_t)r * 64 + tx * 4] = u;
        }
    }
}

// ---------------------------------------------------------------------------
// CSR build: histogram -> multi-block scan -> packed bucket fill
// ---------------------------------------------------------------------------
__global__ __launch_bounds__(256) void hist_kernel(const int* __restrict__ dst,
                                                   int* __restrict__ counts) {
    int e = blockIdx.x * 256 + threadIdx.x;
    if (e < N_EDGES) atomicAdd(&counts[dst[e]], 1);
}

// A: per-block (1024 ints) sums
__global__ __launch_bounds__(256) void scan_bsum_kernel(const int* __restrict__ counts,
                                                        int* __restrict__ bsum) {
    __shared__ int wsh[4];
    const int t = threadIdx.x, lane = t & 63, wv = t >> 6;
    int idx = blockIdx.x * 1024 + t * 4;
    int s = 0;
    if (idx < N_NODES) {   // N_NODES % 4 == 0 -> whole int4 in-bounds
        int4 c = *(const int4*)(counts + idx);
        s = c.x + c.y + c.z + c.w;
    }
#pragma unroll
    for (int off = 32; off > 0; off >>= 1) s += __shfl_down(s, off, 64);
    if (lane == 0) wsh[wv] = s;
    __syncthreads();
    if (t == 0) bsum[blockIdx.x] = wsh[0] + wsh[1] + wsh[2] + wsh[3];
}

// B: one wave scans the 98 block sums -> exclusive boffset; set row_ptr[N]
__global__ __launch_bounds__(64) void scan_boff_kernel(const int* __restrict__ bsum,
                                                       int* __restrict__ boffset,
                                                       int* __restrict__ row_ptr) {
    const int t = threadIdx.x;  // 0..63, each owns elements 2t, 2t+1
    int c0 = (2 * t     < NBLK_SCAN) ? bsum[2 * t]     : 0;
    int c1 = (2 * t + 1 < NBLK_SCAN) ? bsum[2 * t + 1] : 0;
    int s = c0 + c1;
    int v = s;
#pragma unroll
    for (int off = 1; off < 64; off <<= 1) {
        int u = __shfl_up(v, off, 64);
        if (t >= off) v += u;
    }
    int excl = v - s;
    if (2 * t     < NBLK_SCAN) boffset[2 * t]     = excl;
    if (2 * t + 1 < NBLK_SCAN) boffset[2 * t + 1] = excl + c0;
    if (t == 0) row_ptr[N_NODES] = N_EDGES;
}

// C: per-block exclusive rescan + boffset -> row_ptr, cursor
__global__ __launch_bounds__(256) void scan_write_kernel(const int* __restrict__ counts,
                                                         const int* __restrict__ boffset,
                                                         int* __restrict__ row_ptr,
                                                         int* __restrict__ cursor) {
    __shared__ int wsh[4];
    const int t = threadIdx.x, lane = t & 63, wv = t >> 6;
    int idx = blockIdx.x * 1024 + t * 4;
    int4 c = make_int4(0, 0, 0, 0);
    if (idx < N_NODES) c = *(const int4*)(counts + idx);
    int s = c.x + c.y + c.z + c.w;

    int v = s;
#pragma unroll
    for (int off = 1; off < 64; off <<= 1) {
        int u = __shfl_up(v, off, 64);
        if (lane >= off) v += u;
    }
    if (lane == 63) wsh[wv] = v;
    __syncthreads();
    int wave_excl = 0;
#pragma unroll
    for (int w = 0; w < 4; ++w) wave_excl += (w < wv) ? wsh[w] : 0;

    if (idx < N_NODES) {
        int p = boffset[blockIdx.x] + wave_excl + (v - s);
        int4 r;
        r.x = p;
        r.y = p + c.x;
        r.z = r.y + c.y;
        r.w = r.z + c.z;
        *(int4*)(row_ptr + idx) = r;
        *(int4*)(cursor  + idx) = r;
    }
}

// fill: one packed 8 B store per edge (1 random cache line, not 2)
__global__ __launch_bounds__(256) void fill_kernel(const int* __restrict__ src,
                                                   const int* __restrict__ dst,
                                                   const float* __restrict__ vals,
                                                   int* __restrict__ cursor,
                                                   uint2* __restrict__ ep) {
    int e = blockIdx.x * 256 + threadIdx.x;
    if (e < N_EDGES) {
        int pos = atomicAdd(&cursor[dst[e]], 1);
        ep[pos] = make_uint2((unsigned)src[e], __float_as_uint(vals[e]));
    }
}

// ---------------------------------------------------------------------------
// Gather: one wave per node, bf16 h rows (256 B = 64 lanes x 1 uint).
// ---------------------------------------------------------------------------
__global__ __launch_bounds__(256) void gather_bf16_kernel(
        const unsigned int* __restrict__ hbits,  // [N_NODES][64]
        const int* __restrict__ row_ptr,
        const uint2* __restrict__ ep,
        float2* __restrict__ out2)
{
    const int lane = threadIdx.x & 63;
    const int node = blockIdx.x * 4 + (threadIdx.x >> 6);
    if (node >= N_NODES) return;

    const int jb = row_ptr[node];
    const int je = row_ptr[node + 1];

    float ax0 = 0.f, ay0 = 0.f, ax1 = 0.f, ay1 = 0.f;

    int j = jb;
    for (; j + 1 < je; j += 2) {
        uint2 e0 = ep[j], e1 = ep[j + 1];
        unsigned b0 = hbits[(size_t)e0.x * 64 + lane];
        unsigned b1 = hbits[(size_t)e1.x * 64 + lane];
        float v0 = __uint_as_float(e0.y), v1 = __uint_as_float(e1.y);
        ax0 += v0 * __uint_as_float(b0 << 16);
        ay0 += v0 * __uint_as_float(b0 & 0xffff0000u);
        ax1 += v1 * __uint_as_float(b1 << 16);
        ay1 += v1 * __uint_as_float(b1 & 0xffff0000u);
    }
    if (j < je) {
        uint2 e0 = ep[j];
        unsigned b0 = hbits[(size_t)e0.x * 64 + lane];
        float v0 = __uint_as_float(e0.y);
        ax0 += v0 * __uint_as_float(b0 << 16);
        ay0 += v0 * __uint_as_float(b0 & 0xffff0000u);
    }
    out2[(size_t)node * 64 + lane] = make_float2(ax0 + ax1, ay0 + ay1);
}

// ---------------------------------------------------------------------------
// Fallback scatter (atomic) on bf16 h, if workspace too small
// ---------------------------------------------------------------------------
__global__ __launch_bounds__(256) void scatter_kernel(
        const unsigned int* __restrict__ hbits, const float* __restrict__ vals,
        const int* __restrict__ src, const int* __restrict__ dst,
        float* __restrict__ out)
{
    const int lane = threadIdx.x & 63;
    int e = (blockIdx.x * 256 + threadIdx.x) >> 6;
    if (e >= N_EDGES) return;
    const int   s = src[e];
    const int   d = dst[e];
    const float v = vals[e];
    unsigned b = hbits[(size_t)s * 64 + lane];
    float* op = out + (size_t)d * DIM + lane * 2;
    atomicAdd(op + 0, v * __uint_as_float(b << 16));
    atomicAdd(op + 1, v * __uint_as_float(b & 0xffff0000u));
}

// ---------------------------------------------------------------------------
extern "C" void kernel_launch(void* const* d_in, const int* in_sizes, int n_in,
                              void* d_out, int out_size, void* d_ws, size_t ws_size,
                              hipStream_t stream) {
    const float* x    = (const float*)d_in[0];
    const float* W    = (const float*)d_in[1];
    const float* vals = (const float*)d_in[2];
    const int*   src  = (const int*)d_in[3];
    const int*   dst  = (const int*)d_in[4];
    float* out = (float*)d_out;

    char* ws = (char*)d_ws;
    unsigned* hbits  = (unsigned*)(ws + OFF_H);
    int*   row_ptr   = (int*)  (ws + OFF_ROWPTR);
    int*   cursor    = (int*)  (ws + OFF_CURSOR);
    int*   counts    = (int*)  (ws + OFF_COUNTS);
    int*   bsum      = (int*)  (ws + OFF_BSUM);
    int*   boffset   = bsum + 128;
    uint2* ep        = (uint2*)(ws + OFF_EPACK);

    // GEMM: h = bf16(x @ W^T)
    gemm_tiled_kernel<<<(N_NODES + GR - 1) / GR, 256, 0, stream>>>(
        (const float4*)x, (const float4*)W, hbits);

    if (ws_size >= (size_t)WS_NEED) {
        zero_counts_kernel<<<(100032 / 4 + 255) / 256, 256, 0, stream>>>((int4*)counts);
        hist_kernel<<<(N_EDGES + 255) / 256, 256, 0, stream>>>(dst, counts);
        scan_bsum_kernel<<<NBLK_SCAN, 256, 0, stream>>>(counts, bsum);
        scan_boff_kernel<<<1, 64, 0, stream>>>(bsum, boffset, row_ptr);
        scan_write_kernel<<<NBLK_SCAN, 256, 0, stream>>>(counts, boffset, row_ptr, cursor);
        fill_kernel<<<(N_EDGES + 255) / 256, 256, 0, stream>>>(src, dst, vals, cursor, ep);
        gather_bf16_kernel<<<(N_NODES + 3) / 4, 256, 0, stream>>>(
            hbits, row_ptr, ep, (float2*)out);
    } else {
        zero_out_kernel<<<(N_NODES * DIM / 4 + 255) / 256, 256, 0, stream>>>((float4*)out);
        scatter_kernel<<<(N_EDGES * 64 + 255) / 256, 256, 0, stream>>>(
            hbits, vals, src, dst, out);
    }
}